// Round 2
// baseline (766.533 us; speedup 1.0000x reference)
//
#include <hip/hip_runtime.h>
#include <hip/hip_bf16.h>
#include <cstdint>

#define DEVINL __device__ __forceinline__

typedef __attribute__((ext_vector_type(4))) float f32x4;
typedef __attribute__((ext_vector_type(8))) __bf16 bf16x8_t;
typedef __attribute__((ext_vector_type(8))) unsigned short us8;

#define NB   8
#define CIN  320
#define CH   512
#define NPIX 4096
#define PTOT 32768
#define KY   832

DEVINL unsigned short f2bf(float f) {
  union { float f; uint32_t u; } v; v.f = f;
  uint32_t u = v.u;
  uint32_t r = (u + 0x7FFFu + ((u >> 16) & 1u)) >> 16;
  return (unsigned short)r;
}
DEVINL float bf2f(unsigned short h) {
  union { uint32_t u; float f; } v; v.u = ((uint32_t)h) << 16;
  return v.f;
}
DEVINL float sigmoidf_(float x) { return 1.f / (1.f + __expf(-x)); }
DEVINL float relu6f_(float x) { return fminf(fmaxf(x, 0.f), 6.f); }

DEVINL void gload_lds16(const void* g, void* l) {
  __builtin_amdgcn_global_load_lds(
      (const __attribute__((address_space(1))) uint32_t*)g,
      (__attribute__((address_space(3))) uint32_t*)l, 16, 0, 0);
}

// ---------------- weight convert (f32 -> bf16) ----------------
__global__ __launch_bounds__(256) void wconv_kernel(
    const float* __restrict__ Wy, const float* __restrict__ Wbi,
    const float* __restrict__ Wbf, const float* __restrict__ Wbc,
    const float* __restrict__ Wbo,
    unsigned short* __restrict__ Wy_bf, unsigned short* __restrict__ Wg_bf)
{
  int u = blockIdx.x * 256 + threadIdx.x;
  if (u < 512 * 832) Wy_bf[u] = f2bf(Wy[u]);
  if (u < 4 * 262144) {
    int g = u >> 18, r = u & 262143;
    const float* W = (g == 0) ? Wbi : (g == 1) ? Wbf : (g == 2) ? Wbc : Wbo;
    Wg_bf[u] = f2bf(W[r]);
  }
}

// ---------------- dw3x3(x)+bias, write transposed Y_T[p][ci] ----------------
__global__ __launch_bounds__(256) void dwx_kernel(
    const float* __restrict__ x, const float* __restrict__ Wdw,
    const float* __restrict__ Wdwb, unsigned short* __restrict__ Y_T)
{
  __shared__ unsigned short tile[64][65];
  const int y = blockIdx.x, cc = blockIdx.y, n = blockIdx.z;
  const int tid = threadIdx.x;
  const int cl = tid >> 2, xp = (tid & 3) << 4;
  const int ci = cc * 64 + cl;
  const float* plane = x + ((long)(n * CIN + ci) << 12);
  float wv[9];
#pragma unroll
  for (int q = 0; q < 9; ++q) wv[q] = Wdw[ci * 9 + q];
  const float bias = Wdwb[ci];
  float r[3][18];
#pragma unroll
  for (int dy = 0; dy < 3; ++dy) {
    const int yy = y + dy - 1;
    const bool yok = (yy >= 0) && (yy < 64);
#pragma unroll
    for (int q = 0; q < 18; ++q) {
      const int xx = xp + q - 1;
      r[dy][q] = (yok && xx >= 0 && xx < 64) ? plane[(yy << 6) + xx] : 0.f;
    }
  }
#pragma unroll
  for (int u = 0; u < 16; ++u) {
    float a = bias;
#pragma unroll
    for (int dy = 0; dy < 3; ++dy)
#pragma unroll
      for (int dx = 0; dx < 3; ++dx)
        a += wv[dy * 3 + dx] * r[dy][u + dx];
    tile[cl][xp + u] = f2bf(a);
  }
  __syncthreads();
  const int px = tid >> 2, cg = (tid & 3) << 4;
  us8 v0, v1;
#pragma unroll
  for (int j = 0; j < 8; ++j) v0[j] = tile[cg + j][px];
#pragma unroll
  for (int j = 0; j < 8; ++j) v1[j] = tile[cg + 8 + j][px];
  const long p = ((long)n << 12) + (y << 6) + px;
  unsigned short* dst = Y_T + p * KY + cc * 64 + cg;
  *(us8*)dst = v0;
  *(us8*)(dst + 8) = v1;
}

// ---------------- h -> bf16, write transposed into Y_T cols 320.. ----------------
__global__ __launch_bounds__(256) void htr_kernel(
    const float* __restrict__ h, unsigned short* __restrict__ Y_T)
{
  __shared__ unsigned short tile[64][65];
  const int y = blockIdx.x, cc = blockIdx.y, n = blockIdx.z;
  const int tid = threadIdx.x;
  const int cl = tid >> 2, xp = (tid & 3) << 4;
  const int chn = cc * 64 + cl;
  const float* src = h + ((long)(n * CH + chn) << 12) + (y << 6) + xp;
#pragma unroll
  for (int u = 0; u < 16; u += 4) {
    f32x4 a = *(const f32x4*)(src + u);
#pragma unroll
    for (int j = 0; j < 4; ++j) tile[cl][xp + u + j] = f2bf(a[j]);
  }
  __syncthreads();
  const int px = tid >> 2, cg = (tid & 3) << 4;
  us8 v0, v1;
#pragma unroll
  for (int j = 0; j < 8; ++j) v0[j] = tile[cg + j][px];
#pragma unroll
  for (int j = 0; j < 8; ++j) v1[j] = tile[cg + 8 + j][px];
  const long p = ((long)n << 12) + (y << 6) + px;
  unsigned short* dst = Y_T + p * KY + CIN + cc * 64 + cg;
  *(us8*)dst = v0;
  *(us8*)(dst + 8) = v1;
}

// ---------------- dw3x3(i) (bf16 in), write transposed b_T[p][ci] ----------------
__global__ __launch_bounds__(256) void dwi_kernel(
    const unsigned short* __restrict__ ib, const float* __restrict__ Wi,
    unsigned short* __restrict__ b_T)
{
  __shared__ unsigned short tile[64][65];
  const int y = blockIdx.x, cc = blockIdx.y, n = blockIdx.z;
  const int tid = threadIdx.x;
  const int cl = tid >> 2, xp = (tid & 3) << 4;
  const int ci = cc * 64 + cl;
  const unsigned short* plane = ib + ((long)(n * CH + ci) << 12);
  float wv[9];
#pragma unroll
  for (int q = 0; q < 9; ++q) wv[q] = Wi[ci * 9 + q];
  float r[3][18];
#pragma unroll
  for (int dy = 0; dy < 3; ++dy) {
    const int yy = y + dy - 1;
    const bool yok = (yy >= 0) && (yy < 64);
#pragma unroll
    for (int q = 0; q < 18; ++q) {
      const int xx = xp + q - 1;
      r[dy][q] = (yok && xx >= 0 && xx < 64) ? bf2f(plane[(yy << 6) + xx]) : 0.f;
    }
  }
#pragma unroll
  for (int u = 0; u < 16; ++u) {
    float a = 0.f;
#pragma unroll
    for (int dy = 0; dy < 3; ++dy)
#pragma unroll
      for (int dx = 0; dx < 3; ++dx)
        a += wv[dy * 3 + dx] * r[dy][u + dx];
    tile[cl][xp + u] = f2bf(a);
  }
  __syncthreads();
  const int px = tid >> 2, cg = (tid & 3) << 4;
  us8 v0, v1;
#pragma unroll
  for (int j = 0; j < 8; ++j) v0[j] = tile[cg + j][px];
#pragma unroll
  for (int j = 0; j < 8; ++j) v1[j] = tile[cg + 8 + j][px];
  const long p = ((long)n << 12) + (y << 6) + px;
  unsigned short* dst = b_T + p * CH + cc * 64 + cg;
  *(us8*)dst = v0;
  *(us8*)(dst + 8) = v1;
}

// ---------------- bf16 MFMA GEMM1: i = Wy * Y_T^T + bias, out NCHW bf16 ----------------
// 128x128 tile, BK=32, 4 waves (2x2), double-buffered LDS staged via
// global_load_lds(16B) with source-side XOR chunk swizzle (T2/m173 pattern).
__global__ __launch_bounds__(256, 2) void gemm1_kernel(
    const unsigned short* __restrict__ A,   // Wy_bf [512][832]
    const unsigned short* __restrict__ Bt,  // Y_T [32768][832]
    const float* __restrict__ bias,
    unsigned short* __restrict__ out)       // i_b NCHW bf16
{
  __shared__ unsigned short lds[2][2][4096];
  const int nwg = gridDim.x;               // 1024, %8==0
  const int bid = blockIdx.x;
  const int wg  = (bid & 7) * (nwg >> 3) + (bid >> 3);
  const int m_t = wg & 3;
  const int n_t = wg >> 2;
  const int m0 = m_t << 7;
  const long p0 = (long)n_t << 7;

  const int tid = threadIdx.x;
  const int w = tid >> 6, l = tid & 63;
  const int lm = l & 15, lk = l >> 4;

  const int rr = w * 16 + (l >> 2);
  const int r0 = rr, r1 = rr + 64;
  const int c0 = ((l & 3) ^ ((r0 >> 1) & 3)) & 3;
  const int c1 = ((l & 3) ^ ((r1 >> 1) & 3)) & 3;
  const unsigned short* gA0 = A + (long)(m0 + r0) * KY + c0 * 8;
  const unsigned short* gA1 = A + (long)(m0 + r1) * KY + c1 * 8;
  const unsigned short* gB0 = Bt + (p0 + r0) * KY + c0 * 8;
  const unsigned short* gB1 = Bt + (p0 + r1) * KY + c1 * 8;

  char* ldsb = (char*)&lds[0][0][0];

  const int wm = w >> 1, wn = w & 1;
  const int cch = ((lk ^ (lm >> 1)) & 3) * 16;
  int aoff[4], boff[4];
#pragma unroll
  for (int q = 0; q < 4; ++q) {
    aoff[q] = (wm * 64 + q * 16 + lm) * 64 + cch;
    boff[q] = 8192 + (wn * 64 + q * 16 + lm) * 64 + cch;
  }

  f32x4 acc[4][4] = {};

  {
    char* nb = ldsb;
    gload_lds16(gA0, nb + w * 1024);
    gload_lds16(gA1, nb + w * 1024 + 4096);
    gload_lds16(gB0, nb + 8192 + w * 1024);
    gload_lds16(gB1, nb + 8192 + w * 1024 + 4096);
  }
  __syncthreads();

#pragma unroll 2
  for (int kt = 0; kt < 26; ++kt) {
    if (kt + 1 < 26) {
      const int ko = (kt + 1) * 32;
      char* nb = ldsb + ((kt + 1) & 1) * 16384;
      gload_lds16(gA0 + ko, nb + w * 1024);
      gload_lds16(gA1 + ko, nb + w * 1024 + 4096);
      gload_lds16(gB0 + ko, nb + 8192 + w * 1024);
      gload_lds16(gB1 + ko, nb + 8192 + w * 1024 + 4096);
    }
    const char* cb = ldsb + (kt & 1) * 16384;
    bf16x8_t af[4], bfv[4];
#pragma unroll
    for (int q = 0; q < 4; ++q) af[q] = *(const bf16x8_t*)(cb + aoff[q]);
#pragma unroll
    for (int q = 0; q < 4; ++q) bfv[q] = *(const bf16x8_t*)(cb + boff[q]);
#pragma unroll
    for (int mf = 0; mf < 4; ++mf)
#pragma unroll
      for (int nf = 0; nf < 4; ++nf)
        acc[mf][nf] = __builtin_amdgcn_mfma_f32_16x16x32_bf16(
            af[mf], bfv[nf], acc[mf][nf], 0, 0, 0);
    __syncthreads();
  }

  // C/D layout: col=lane&15, row=(lane>>4)*4+j (m89/m91)
#pragma unroll
  for (int mf = 0; mf < 4; ++mf) {
#pragma unroll
    for (int nf = 0; nf < 4; ++nf) {
#pragma unroll
      for (int j = 0; j < 4; ++j) {
        const int m = m0 + wm * 64 + mf * 16 + lk * 4 + j;
        const long p = p0 + wn * 64 + nf * 16 + lm;
        const float v = acc[mf][nf][j] + bias[m];
        const long oidx = (p >> 12) * (long)(CH * NPIX) + (long)m * NPIX + (p & 4095);
        out[oidx] = f2bf(v);
      }
    }
  }
}

// ---------------- fused gate GEMMs + LSTM elementwise ----------------
// For a 128-channel x 128-pixel tile, run the K=512 loop 4x (gate order
// c,i,f,o) over the same B-tile, carrying running state t:
//   t=relu6(zc); t*=sig(zi); cc=sig(zf)*c+t (store cc, t=relu6(cc));
//   ch=sig(zo)*t (store ch).  z never hits memory.
__global__ __launch_bounds__(256, 2) void gemm_gates_kernel(
    const unsigned short* __restrict__ Wg,  // [4][512][512] bf16, order i,f,c,o
    const unsigned short* __restrict__ Bt,  // b_T [32768][512]
    const float* __restrict__ cin,
    float* __restrict__ outp)               // [ch | cc] f32 NCHW
{
  __shared__ unsigned short lds[2][2][4096];
  const int nwg = gridDim.x;               // 1024, %8==0
  const int bid = blockIdx.x;
  const int wg  = (bid & 7) * (nwg >> 3) + (bid >> 3);
  const int m_t = wg & 3;
  const int n_t = wg >> 2;
  const int m0 = m_t << 7;
  const long p0 = (long)n_t << 7;

  const int tid = threadIdx.x;
  const int w = tid >> 6, l = tid & 63;
  const int lm = l & 15, lk = l >> 4;

  const int rr = w * 16 + (l >> 2);
  const int r0 = rr, r1 = rr + 64;
  const int c0 = ((l & 3) ^ ((r0 >> 1) & 3)) & 3;
  const int c1 = ((l & 3) ^ ((r1 >> 1) & 3)) & 3;
  const unsigned short* gB0 = Bt + (p0 + r0) * CH + c0 * 8;
  const unsigned short* gB1 = Bt + (p0 + r1) * CH + c1 * 8;
  const long aoffg0 = (long)(m0 + r0) * CH + c0 * 8;
  const long aoffg1 = (long)(m0 + r1) * CH + c1 * 8;

  char* ldsb = (char*)&lds[0][0][0];

  const int wm = w >> 1, wn = w & 1;
  const int cch = ((lk ^ (lm >> 1)) & 3) * 16;
  int aoff[4], boff[4];
#pragma unroll
  for (int q = 0; q < 4; ++q) {
    aoff[q] = (wm * 64 + q * 16 + lm) * 64 + cch;
    boff[q] = 8192 + (wn * 64 + q * 16 + lm) * 64 + cch;
  }

  f32x4 t[4][4];

  for (int gs = 0; gs < 4; ++gs) {
    const int g = (0x3102 >> (gs << 2)) & 3;  // gate order c(2), i(0), f(1), o(3)
    const unsigned short* A = Wg + ((long)g << 18);
    const unsigned short* gA0 = A + aoffg0;
    const unsigned short* gA1 = A + aoffg1;

    f32x4 acc[4][4] = {};

    {
      char* nb = ldsb;
      gload_lds16(gA0, nb + w * 1024);
      gload_lds16(gA1, nb + w * 1024 + 4096);
      gload_lds16(gB0, nb + 8192 + w * 1024);
      gload_lds16(gB1, nb + 8192 + w * 1024 + 4096);
    }
    __syncthreads();

#pragma unroll 2
    for (int kt = 0; kt < 16; ++kt) {
      if (kt + 1 < 16) {
        const int ko = (kt + 1) * 32;
        char* nb = ldsb + ((kt + 1) & 1) * 16384;
        gload_lds16(gA0 + ko, nb + w * 1024);
        gload_lds16(gA1 + ko, nb + w * 1024 + 4096);
        gload_lds16(gB0 + ko, nb + 8192 + w * 1024);
        gload_lds16(gB1 + ko, nb + 8192 + w * 1024 + 4096);
      }
      const char* cb = ldsb + (kt & 1) * 16384;
      bf16x8_t af[4], bfv[4];
#pragma unroll
      for (int q = 0; q < 4; ++q) af[q] = *(const bf16x8_t*)(cb + aoff[q]);
#pragma unroll
      for (int q = 0; q < 4; ++q) bfv[q] = *(const bf16x8_t*)(cb + boff[q]);
#pragma unroll
      for (int mf = 0; mf < 4; ++mf)
#pragma unroll
        for (int nf = 0; nf < 4; ++nf)
          acc[mf][nf] = __builtin_amdgcn_mfma_f32_16x16x32_bf16(
              af[mf], bfv[nf], acc[mf][nf], 0, 0, 0);
      __syncthreads();
    }

    // epilogue per gate stage (wave-uniform branches; t statically indexed)
#pragma unroll
    for (int mf = 0; mf < 4; ++mf) {
#pragma unroll
      for (int nf = 0; nf < 4; ++nf) {
        if (gs == 0) {          // z_c
#pragma unroll
          for (int j = 0; j < 4; ++j)
            t[mf][nf][j] = relu6f_(acc[mf][nf][j]);
        } else if (gs == 1) {   // z_i
#pragma unroll
          for (int j = 0; j < 4; ++j)
            t[mf][nf][j] *= sigmoidf_(acc[mf][nf][j]);
        } else if (gs == 2) {   // z_f : cc = sig(zf)*c + t; store cc; t = relu6(cc)
#pragma unroll
          for (int j = 0; j < 4; ++j) {
            const int m = m0 + wm * 64 + mf * 16 + lk * 4 + j;
            const long p = p0 + wn * 64 + nf * 16 + lm;
            const long cidx = (p >> 12) * (long)(CH * NPIX) + (long)m * NPIX + (p & 4095);
            const float ccv = sigmoidf_(acc[mf][nf][j]) * cin[cidx] + t[mf][nf][j];
            outp[(long)NB * CH * NPIX + cidx] = ccv;
            t[mf][nf][j] = relu6f_(ccv);
          }
        } else {                // z_o : ch = sig(zo)*t; store ch
#pragma unroll
          for (int j = 0; j < 4; ++j) {
            const int m = m0 + wm * 64 + mf * 16 + lk * 4 + j;
            const long p = p0 + wn * 64 + nf * 16 + lm;
            const long cidx = (p >> 12) * (long)(CH * NPIX) + (long)m * NPIX + (p & 4095);
            outp[cidx] = sigmoidf_(acc[mf][nf][j]) * t[mf][nf][j];
          }
        }
      }
    }
  }
}

// ---------------- launch ----------------
extern "C" void kernel_launch(void* const* d_in, const int* in_sizes, int n_in,
                              void* d_out, int out_size, void* d_ws, size_t ws_size,
                              hipStream_t stream)
{
  const float* x    = (const float*)d_in[0];
  const float* h    = (const float*)d_in[1];
  const float* c    = (const float*)d_in[2];
  const float* Wdw  = (const float*)d_in[3];
  const float* Wdwb = (const float*)d_in[4];
  const float* Wy   = (const float*)d_in[5];
  const float* Wyb  = (const float*)d_in[6];
  const float* Wi   = (const float*)d_in[7];
  const float* Wbi  = (const float*)d_in[8];
  const float* Wbf  = (const float*)d_in[9];
  const float* Wbc  = (const float*)d_in[10];
  const float* Wbo  = (const float*)d_in[11];
  float* outp = (float*)d_out;

  char* ws = (char*)d_ws;
  // workspace layout (bytes), peak ~91.0 MB:
  //   Y_T  [32768][832] bf16 @ 0           (54,525,952)  dead after gemm1
  //   i_b  [8][512][4096] bf16 @ 54,525,952 (33,554,432)  dead after dwi
  //   b_T  [32768][512] bf16 @ 0           (33,554,432)  overlays dead Y_T
  //   Wy_bf @ 88,080,384 (851,968) ; Wg_bf @ 88,932,352 (2,097,152)
  unsigned short* Y_T   = (unsigned short*)(ws);
  unsigned short* i_b   = (unsigned short*)(ws + 54525952);
  unsigned short* b_T   = (unsigned short*)(ws);
  unsigned short* Wy_bf = (unsigned short*)(ws + 88080384);
  unsigned short* Wg_bf = (unsigned short*)(ws + 88932352);

  wconv_kernel<<<4096, 256, 0, stream>>>(Wy, Wbi, Wbf, Wbc, Wbo, Wy_bf, Wg_bf);
  dwx_kernel<<<dim3(64, 5, 8), 256, 0, stream>>>(x, Wdw, Wdwb, Y_T);
  htr_kernel<<<dim3(64, 8, 8), 256, 0, stream>>>(h, Y_T);
  gemm1_kernel<<<1024, 256, 0, stream>>>(Wy_bf, Y_T, Wyb, i_b);
  dwi_kernel<<<dim3(64, 8, 8), 256, 0, stream>>>(i_b, Wi, b_T);
  gemm_gates_kernel<<<1024, 256, 0, stream>>>(Wg_bf, b_T, c, outp);
}

// Round 9
// 547.108 us; speedup vs baseline: 1.4011x; 1.4011x over previous
//
#include <hip/hip_runtime.h>
#include <hip/hip_bf16.h>
#include <cstdint>

#define DEVINL __device__ __forceinline__

typedef __attribute__((ext_vector_type(4))) float f32x4;
typedef __attribute__((ext_vector_type(8))) __bf16 bf16x8_t;
typedef __attribute__((ext_vector_type(8))) unsigned short us8;

#define NB   8
#define CIN  320
#define CH   512
#define NPIX 4096
#define PTOT 32768
#define KY   832

DEVINL unsigned short f2bf(float f) {
  union { float f; uint32_t u; } v; v.f = f;
  uint32_t u = v.u;
  uint32_t r = (u + 0x7FFFu + ((u >> 16) & 1u)) >> 16;
  return (unsigned short)r;
}
DEVINL float bf2f(unsigned short h) {
  union { uint32_t u; float f; } v; v.u = ((uint32_t)h) << 16;
  return v.f;
}
DEVINL float sigmoidf_(float x) { return 1.f / (1.f + __expf(-x)); }
DEVINL float relu6f_(float x) { return fminf(fmaxf(x, 0.f), 6.f); }

DEVINL void gload_lds16(const void* g, void* l) {
  __builtin_amdgcn_global_load_lds(
      (const __attribute__((address_space(1))) uint32_t*)g,
      (__attribute__((address_space(3))) uint32_t*)l, 16, 0, 0);
}

// ---------------- weight convert + gate-interleaved stack ----------------
// Wstack[2048][512]: row m -> T=m>>8, r=m&255, wr=r>>7, rw=r&127,
//   gate g=rw>>5 (0=i,1=f,2=c,3=o), chan = T*64 + wr*32 + (rw&31).
__global__ __launch_bounds__(256) void wconv_kernel(
    const float* __restrict__ Wy, const float* __restrict__ Wbi,
    const float* __restrict__ Wbf, const float* __restrict__ Wbc,
    const float* __restrict__ Wbo,
    unsigned short* __restrict__ Wy_bf, unsigned short* __restrict__ Wstack)
{
  int u = blockIdx.x * 256 + threadIdx.x;
  if (u < 512 * 832) Wy_bf[u] = f2bf(Wy[u]);
  if (u < 2048 * 512) {
    const int m = u >> 9, k = u & 511;
    const int r = m & 255, rw = r & 127;
    const int g = rw >> 5;
    const int chan = (m >> 8) * 64 + ((r >> 7) << 5) + (rw & 31);
    const float* W = (g == 0) ? Wbi : (g == 1) ? Wbf : (g == 2) ? Wbc : Wbo;
    Wstack[u] = f2bf(W[chan * 512 + k]);
  }
}

// ---------------- dw3x3(x)+bias, write transposed Y_T[p][ci] ----------------
__global__ __launch_bounds__(256) void dwx_kernel(
    const float* __restrict__ x, const float* __restrict__ Wdw,
    const float* __restrict__ Wdwb, unsigned short* __restrict__ Y_T)
{
  __shared__ unsigned short tile[64][65];
  const int y = blockIdx.x, cc = blockIdx.y, n = blockIdx.z;
  const int tid = threadIdx.x;
  const int cl = tid >> 2, xp = (tid & 3) << 4;
  const int ci = cc * 64 + cl;
  const float* plane = x + ((long)(n * CIN + ci) << 12);
  float wv[9];
#pragma unroll
  for (int q = 0; q < 9; ++q) wv[q] = Wdw[ci * 9 + q];
  const float bias = Wdwb[ci];
  float r[3][18];
#pragma unroll
  for (int dy = 0; dy < 3; ++dy) {
    const int yy = y + dy - 1;
    const bool yok = (yy >= 0) && (yy < 64);
#pragma unroll
    for (int q = 0; q < 18; ++q) {
      const int xx = xp + q - 1;
      r[dy][q] = (yok && xx >= 0 && xx < 64) ? plane[(yy << 6) + xx] : 0.f;
    }
  }
#pragma unroll
  for (int u = 0; u < 16; ++u) {
    float a = bias;
#pragma unroll
    for (int dy = 0; dy < 3; ++dy)
#pragma unroll
      for (int dx = 0; dx < 3; ++dx)
        a += wv[dy * 3 + dx] * r[dy][u + dx];
    tile[cl][xp + u] = f2bf(a);
  }
  __syncthreads();
  const int px = tid >> 2, cg = (tid & 3) << 4;
  us8 v0, v1;
#pragma unroll
  for (int j = 0; j < 8; ++j) v0[j] = tile[cg + j][px];
#pragma unroll
  for (int j = 0; j < 8; ++j) v1[j] = tile[cg + 8 + j][px];
  const long p = ((long)n << 12) + (y << 6) + px;
  unsigned short* dst = Y_T + p * KY + cc * 64 + cg;
  *(us8*)dst = v0;
  *(us8*)(dst + 8) = v1;
}

// ---------------- h -> bf16, write transposed into Y_T cols 320.. ----------------
__global__ __launch_bounds__(256) void htr_kernel(
    const float* __restrict__ h, unsigned short* __restrict__ Y_T)
{
  __shared__ unsigned short tile[64][65];
  const int y = blockIdx.x, cc = blockIdx.y, n = blockIdx.z;
  const int tid = threadIdx.x;
  const int cl = tid >> 2, xp = (tid & 3) << 4;
  const int chn = cc * 64 + cl;
  const float* src = h + ((long)(n * CH + chn) << 12) + (y << 6) + xp;
#pragma unroll
  for (int u = 0; u < 16; u += 4) {
    f32x4 a = *(const f32x4*)(src + u);
#pragma unroll
    for (int j = 0; j < 4; ++j) tile[cl][xp + u + j] = f2bf(a[j]);
  }
  __syncthreads();
  const int px = tid >> 2, cg = (tid & 3) << 4;
  us8 v0, v1;
#pragma unroll
  for (int j = 0; j < 8; ++j) v0[j] = tile[cg + j][px];
#pragma unroll
  for (int j = 0; j < 8; ++j) v1[j] = tile[cg + 8 + j][px];
  const long p = ((long)n << 12) + (y << 6) + px;
  unsigned short* dst = Y_T + p * KY + CIN + cc * 64 + cg;
  *(us8*)dst = v0;
  *(us8*)(dst + 8) = v1;
}

// ---------------- dw3x3(i) (bf16 in), write transposed b_T[p][ci] ----------------
__global__ __launch_bounds__(256) void dwi_kernel(
    const unsigned short* __restrict__ ib, const float* __restrict__ Wi,
    unsigned short* __restrict__ b_T)
{
  __shared__ unsigned short tile[64][65];
  const int y = blockIdx.x, cc = blockIdx.y, n = blockIdx.z;
  const int tid = threadIdx.x;
  const int cl = tid >> 2, xp = (tid & 3) << 4;
  const int ci = cc * 64 + cl;
  const unsigned short* plane = ib + ((long)(n * CH + ci) << 12);
  float wv[9];
#pragma unroll
  for (int q = 0; q < 9; ++q) wv[q] = Wi[ci * 9 + q];
  float r[3][18];
#pragma unroll
  for (int dy = 0; dy < 3; ++dy) {
    const int yy = y + dy - 1;
    const bool yok = (yy >= 0) && (yy < 64);
#pragma unroll
    for (int q = 0; q < 18; ++q) {
      const int xx = xp + q - 1;
      r[dy][q] = (yok && xx >= 0 && xx < 64) ? bf2f(plane[(yy << 6) + xx]) : 0.f;
    }
  }
#pragma unroll
  for (int u = 0; u < 16; ++u) {
    float a = 0.f;
#pragma unroll
    for (int dy = 0; dy < 3; ++dy)
#pragma unroll
      for (int dx = 0; dx < 3; ++dx)
        a += wv[dy * 3 + dx] * r[dy][u + dx];
    tile[cl][xp + u] = f2bf(a);
  }
  __syncthreads();
  const int px = tid >> 2, cg = (tid & 3) << 4;
  us8 v0, v1;
#pragma unroll
  for (int j = 0; j < 8; ++j) v0[j] = tile[cg + j][px];
#pragma unroll
  for (int j = 0; j < 8; ++j) v1[j] = tile[cg + 8 + j][px];
  const long p = ((long)n << 12) + (y << 6) + px;
  unsigned short* dst = b_T + p * CH + cc * 64 + cg;
  *(us8*)dst = v0;
  *(us8*)(dst + 8) = v1;
}

// ---------------- 256x256 bf16 MFMA GEMM, safe 2-phase pipeline ----------
// BM=BN=256, BK=32, 8 waves (2M x 4N), per-wave 128x64, acc[8][4].
// LDS: 2 x (A 16KB + B 16KB) = 64KB static.  T3-minimal recipe (verified
// m248v2): per iter {STAGE next tile into buf^1; ds_read+MFMA from buf;
// __syncthreads()}.  No inline asm / raw barriers — correct by construction
// (each wave's own gload_lds drained by the implicit vmcnt(0); barrier makes
// the staged tile globally visible; loads had the full compute phase to land).
// LDS chunk swizzle: LDS chunk p of row r holds global chunk p ^ ((r>>1)&3),
// applied on the global SOURCE side (m173); de-swizzled on ds_read ->
// 16-lane fragment column spreads over 8 slots = 2-way = free (m136).
// MODE 0: out = bf16 NCHW (i path), bias from aux.
// MODE 1: fused LSTM epilogue. A = Wstack (gate-interleaved M): each wave's
//   rows = 4 gates x 32 channels -> gate = mf>>1 static; aux = cin;
//   outv = [ch | cc] f32 NCHW.
template<int K, int NT, int MTB, int MODE>
__global__ __launch_bounds__(512, 2) void gemm256_kernel(
    const unsigned short* __restrict__ A,
    const unsigned short* __restrict__ Bt,
    const float* __restrict__ aux,
    void* __restrict__ outv)
{
  __shared__ unsigned short lds[2][16384];
  const int nwg = gridDim.x;
  const int bid = blockIdx.x;
  const int wg  = (bid & 7) * (nwg >> 3) + (bid >> 3); // bijective (nwg%8==0)
  const int m_t = wg & ((1 << MTB) - 1);
  const int n_t = wg >> MTB;
  const int m0 = m_t << 8;
  const long p0 = (long)n_t << 8;

  const int tid = threadIdx.x;
  const int wid = tid >> 6, l = tid & 63;
  const int wr = wid >> 2, wc = wid & 3;
  const int lm = l & 15, lk = l >> 4;

  // staging map: thread t covers (row t>>2, lds-chunk t&3); source chunk
  // cx = (t&3) ^ ((row>>1)&3)  ((row+128)>>1 keeps the same low bits).
  const int srow = tid >> 2;
  const int cx   = (tid & 3) ^ ((srow >> 1) & 3);
  const unsigned short* gA0 = A + (long)(m0 + srow) * K + cx * 8;
  const unsigned short* gA1 = A + (long)(m0 + 128 + srow) * K + cx * 8;
  const unsigned short* gB0 = Bt + (p0 + srow) * K + cx * 8;
  const unsigned short* gB1 = Bt + (p0 + 128 + srow) * K + cx * 8;
  char* ldsb = (char*)&lds[0][0];

#define STAGE(buf, kt2) { \
    char* nb = ldsb + (buf) * 32768 + wid * 1024; \
    const int ko = (kt2) * 32; \
    gload_lds16(gA0 + ko, nb); \
    gload_lds16(gA1 + ko, nb + 8192); \
    gload_lds16(gB0 + ko, nb + 16384); \
    gload_lds16(gB1 + ko, nb + 24576); }

  // ds_read offsets (byte, within buffer): A rows 0..255 linear @0, B @16KB.
  int aoff[8], boff[4];
#pragma unroll
  for (int mf = 0; mf < 8; ++mf) {
    const int arow = wr * 128 + mf * 16 + lm;
    aoff[mf] = arow * 64 + ((lk ^ ((lm >> 1) & 3)) * 16);
  }
#pragma unroll
  for (int nf = 0; nf < 4; ++nf) {
    const int brow = wc * 64 + nf * 16 + lm;
    boff[nf] = 16384 + brow * 64 + ((lk ^ ((lm >> 1) & 3)) * 16);
  }

  f32x4 acc[8][4] = {};

  STAGE(0, 0);
  __syncthreads();

#pragma unroll 2
  for (int kt = 0; kt < NT; ++kt) {
    if (kt + 1 < NT) STAGE((kt + 1) & 1, kt + 1);
    const char* cb = ldsb + (kt & 1) * 32768;
    bf16x8_t af[8], bv[4];
#pragma unroll
    for (int mf = 0; mf < 8; ++mf) af[mf] = *(const bf16x8_t*)(cb + aoff[mf]);
#pragma unroll
    for (int nf = 0; nf < 4; ++nf) bv[nf] = *(const bf16x8_t*)(cb + boff[nf]);
#pragma unroll
    for (int mf = 0; mf < 8; ++mf)
#pragma unroll
      for (int nf = 0; nf < 4; ++nf)
        acc[mf][nf] = __builtin_amdgcn_mfma_f32_16x16x32_bf16(
            af[mf], bv[nf], acc[mf][nf], 0, 0, 0);
    __syncthreads();
  }
#undef STAGE

  if (MODE == 0) {
    unsigned short* out = (unsigned short*)outv;
#pragma unroll
    for (int mf = 0; mf < 8; ++mf) {
#pragma unroll
      for (int nf = 0; nf < 4; ++nf) {
#pragma unroll
        for (int j = 0; j < 4; ++j) {
          const int m = m0 + wr * 128 + mf * 16 + lk * 4 + j;
          const long p = p0 + wc * 64 + nf * 16 + lm;
          const float v = acc[mf][nf][j] + aux[m];
          const long oidx = (p >> 12) * (long)(CH * NPIX) + (long)m * NPIX + (p & 4095);
          out[oidx] = f2bf(v);
        }
      }
    }
  } else {
    float* outp = (float*)outv;
    const long CCOFF = (long)NB * CH * NPIX;
#pragma unroll
    for (int sub = 0; sub < 2; ++sub) {
#pragma unroll
      for (int nf = 0; nf < 4; ++nf) {
#pragma unroll
        for (int j = 0; j < 4; ++j) {
          const int chan = (m0 >> 2) + wr * 32 + sub * 16 + lk * 4 + j;
          const long p = p0 + wc * 64 + nf * 16 + lm;
          const long cidx = (p >> 12) * (long)(CH * NPIX) + (long)chan * NPIX + (p & 4095);
          const float zi = acc[0 + sub][nf][j];
          const float zf = acc[2 + sub][nf][j];
          const float zc = acc[4 + sub][nf][j];
          const float zo = acc[6 + sub][nf][j];
          const float ccv = sigmoidf_(zf) * aux[cidx] + sigmoidf_(zi) * relu6f_(zc);
          outp[CCOFF + cidx] = ccv;
          outp[cidx] = sigmoidf_(zo) * relu6f_(ccv);
        }
      }
    }
  }
}

// ---------------- launch ----------------
extern "C" void kernel_launch(void* const* d_in, const int* in_sizes, int n_in,
                              void* d_out, int out_size, void* d_ws, size_t ws_size,
                              hipStream_t stream)
{
  const float* x    = (const float*)d_in[0];
  const float* h    = (const float*)d_in[1];
  const float* c    = (const float*)d_in[2];
  const float* Wdw  = (const float*)d_in[3];
  const float* Wdwb = (const float*)d_in[4];
  const float* Wy   = (const float*)d_in[5];
  const float* Wyb  = (const float*)d_in[6];
  const float* Wi   = (const float*)d_in[7];
  const float* Wbi  = (const float*)d_in[8];
  const float* Wbf  = (const float*)d_in[9];
  const float* Wbc  = (const float*)d_in[10];
  const float* Wbo  = (const float*)d_in[11];
  float* outp = (float*)d_out;

  char* ws = (char*)d_ws;
  // workspace layout (bytes), peak ~91.0 MB:
  //   Y_T  [32768][832] bf16 @ 0            (54,525,952)  dead after gemm1
  //   i_b  [8][512][4096] bf16 @ 54,525,952 (33,554,432)  dead after dwi
  //   b_T  [32768][512] bf16 @ 0            (33,554,432)  overlays dead Y_T
  //   Wy_bf @ 88,080,384 (851,968) ; Wstack @ 88,932,352 (2,097,152)
  unsigned short* Y_T    = (unsigned short*)(ws);
  unsigned short* i_b    = (unsigned short*)(ws + 54525952);
  unsigned short* b_T    = (unsigned short*)(ws);
  unsigned short* Wy_bf  = (unsigned short*)(ws + 88080384);
  unsigned short* Wstack = (unsigned short*)(ws + 88932352);

  wconv_kernel<<<4096, 256, 0, stream>>>(Wy, Wbi, Wbf, Wbc, Wbo, Wy_bf, Wstack);
  dwx_kernel<<<dim3(64, 5, 8), 256, 0, stream>>>(x, Wdw, Wdwb, Y_T);
  htr_kernel<<<dim3(64, 8, 8), 256, 0, stream>>>(h, Y_T);
  gemm256_kernel<KY, 26, 1, 0><<<256, 512, 0, stream>>>(Wy_bf, Y_T, Wyb, i_b);
  dwi_kernel<<<dim3(64, 8, 8), 256, 0, stream>>>(i_b, Wi, b_T);
  gemm256_kernel<CH, 16, 3, 1><<<1024, 512, 0, stream>>>(Wstack, b_T, c, outp);
}

// Round 10
// 409.768 us; speedup vs baseline: 1.8707x; 1.3352x over previous
//
#include <hip/hip_runtime.h>
#include <hip/hip_bf16.h>
#include <cstdint>

#define DEVINL __device__ __forceinline__

typedef __attribute__((ext_vector_type(4))) float f32x4;
typedef __attribute__((ext_vector_type(8))) __bf16 bf16x8_t;
typedef __attribute__((ext_vector_type(8))) unsigned short us8;

#define NB   8
#define CIN  320
#define CH   512
#define NPIX 4096
#define PTOT 32768
#define KY   832

DEVINL unsigned short f2bf(float f) {
  union { float f; uint32_t u; } v; v.f = f;
  uint32_t u = v.u;
  uint32_t r = (u + 0x7FFFu + ((u >> 16) & 1u)) >> 16;
  return (unsigned short)r;
}
DEVINL float bf2f(unsigned short h) {
  union { uint32_t u; float f; } v; v.u = ((uint32_t)h) << 16;
  return v.f;
}
DEVINL float sigmoidf_(float x) { return 1.f / (1.f + __expf(-x)); }
DEVINL float relu6f_(float x) { return fminf(fmaxf(x, 0.f), 6.f); }

DEVINL void gload_lds16(const void* g, void* l) {
  __builtin_amdgcn_global_load_lds(
      (const __attribute__((address_space(1))) uint32_t*)g,
      (__attribute__((address_space(3))) uint32_t*)l, 16, 0, 0);
}

// ---------------- weight convert + gate-interleaved stack ----------------
// Wstack[2048][512]: row m -> T=m>>8, r=m&255, wr=r>>7, rw=r&127,
//   gate g=rw>>5 (0=i,1=f,2=c,3=o), chan = T*64 + wr*32 + (rw&31).
__global__ __launch_bounds__(256) void wconv_kernel(
    const float* __restrict__ Wy, const float* __restrict__ Wbi,
    const float* __restrict__ Wbf, const float* __restrict__ Wbc,
    const float* __restrict__ Wbo,
    unsigned short* __restrict__ Wy_bf, unsigned short* __restrict__ Wstack)
{
  int u = blockIdx.x * 256 + threadIdx.x;
  if (u < 512 * 832) Wy_bf[u] = f2bf(Wy[u]);
  if (u < 2048 * 512) {
    const int m = u >> 9, k = u & 511;
    const int r = m & 255, rw = r & 127;
    const int g = rw >> 5;
    const int chan = (m >> 8) * 64 + ((r >> 7) << 5) + (rw & 31);
    const float* W = (g == 0) ? Wbi : (g == 1) ? Wbf : (g == 2) ? Wbc : Wbo;
    Wstack[u] = f2bf(W[chan * 512 + k]);
  }
}

// ---------------- h -> bf16, write transposed into Y_T cols 320.. ----------------
__global__ __launch_bounds__(256) void htr_kernel(
    const float* __restrict__ h, unsigned short* __restrict__ Y_T)
{
  __shared__ unsigned short tile[64][65];
  const int y = blockIdx.x, cc = blockIdx.y, n = blockIdx.z;
  const int tid = threadIdx.x;
  const int cl = tid >> 2, xp = (tid & 3) << 4;
  const int chn = cc * 64 + cl;
  const float* src = h + ((long)(n * CH + chn) << 12) + (y << 6) + xp;
#pragma unroll
  for (int u = 0; u < 16; u += 4) {
    f32x4 a = *(const f32x4*)(src + u);
#pragma unroll
    for (int j = 0; j < 4; ++j) tile[cl][xp + u + j] = f2bf(a[j]);
  }
  __syncthreads();
  const int px = tid >> 2, cg = (tid & 3) << 4;
  us8 v0, v1;
#pragma unroll
  for (int j = 0; j < 8; ++j) v0[j] = tile[cg + j][px];
#pragma unroll
  for (int j = 0; j < 8; ++j) v1[j] = tile[cg + 8 + j][px];
  const long p = ((long)n << 12) + (y << 6) + px;
  unsigned short* dst = Y_T + p * KY + CIN + cc * 64 + cg;
  *(us8*)dst = v0;
  *(us8*)(dst + 8) = v1;
}

// ---------------- unified dw3x3, vector loads, 2 output rows/thread --------
// Thread: channel ch = tid>>2 (of 64-ch group), x-range xp..xp+15.
// Loads rows y0-1..y0+2, cols xp-1..xp+16 as {1 scalar edge, 4x16B, 1 scalar
// edge} per row -> rowv[4][18] f32 regs (all static-indexed).  Computes 2
// output rows (9-tap each), stages each through the LDS 64x65 transpose tile,
// writes outT[p][ccg*64+cg] as 2x us8 per pixel.  y-edge rows skipped under
// wave-uniform branch (no OOB deref); x-edges predicated scalars.
template<bool F32IN, bool BIAS, int CT, int OSTRIDE>
__global__ __launch_bounds__(256) void dw3x3_kernel(
    const void* __restrict__ inv, const float* __restrict__ W,
    const float* __restrict__ Wb, unsigned short* __restrict__ outT)
{
  __shared__ unsigned short tile[64][65];
  const int yt = blockIdx.x, ccg = blockIdx.y, n = blockIdx.z;
  const int tid = threadIdx.x;
  const int ch = tid >> 2;
  const int xp = (tid & 3) << 4;
  const int y0 = yt << 1;
  const int cglob = ccg * 64 + ch;
  const long plane = ((long)(n * CT + cglob)) << 12;

  float wv[9];
#pragma unroll
  for (int q = 0; q < 9; ++q) wv[q] = W[cglob * 9 + q];
  const float bias = BIAS ? Wb[cglob] : 0.f;

  float rowv[4][18];
#pragma unroll
  for (int r = 0; r < 4; ++r) {
    const int ry = y0 - 1 + r;
    const bool yok = (ry >= 0) && (ry < 64);
    if (F32IN) {
      const float* rp = (const float*)inv + plane + ((long)ry << 6);
      float lf = (yok && xp > 0) ? rp[xp - 1] : 0.f;
      float rt = (yok && xp < 48) ? rp[xp + 16] : 0.f;
      f32x4 c0 = {}, c1 = {}, c2 = {}, c3 = {};
      if (yok) {
        c0 = *(const f32x4*)(rp + xp);
        c1 = *(const f32x4*)(rp + xp + 4);
        c2 = *(const f32x4*)(rp + xp + 8);
        c3 = *(const f32x4*)(rp + xp + 12);
      }
      rowv[r][0] = lf;
#pragma unroll
      for (int j = 0; j < 4; ++j) {
        rowv[r][1 + j] = c0[j];
        rowv[r][5 + j] = c1[j];
        rowv[r][9 + j] = c2[j];
        rowv[r][13 + j] = c3[j];
      }
      rowv[r][17] = rt;
    } else {
      const unsigned short* rp = (const unsigned short*)inv + plane + ((long)ry << 6);
      float lf = (yok && xp > 0) ? bf2f(rp[xp - 1]) : 0.f;
      float rt = (yok && xp < 48) ? bf2f(rp[xp + 16]) : 0.f;
      us8 c01 = {}, c23 = {};
      if (yok) {
        c01 = *(const us8*)(rp + xp);
        c23 = *(const us8*)(rp + xp + 8);
      }
      rowv[r][0] = lf;
#pragma unroll
      for (int j = 0; j < 8; ++j) {
        rowv[r][1 + j] = bf2f(c01[j]);
        rowv[r][9 + j] = bf2f(c23[j]);
      }
      rowv[r][17] = rt;
    }
  }

  float o0[16], o1[16];
#pragma unroll
  for (int u = 0; u < 16; ++u) {
    float a0 = bias, a1 = bias;
#pragma unroll
    for (int dy = 0; dy < 3; ++dy) {
#pragma unroll
      for (int dx = 0; dx < 3; ++dx) {
        const float w = wv[dy * 3 + dx];
        a0 += w * rowv[dy][u + dx];
        a1 += w * rowv[dy + 1][u + dx];
      }
    }
    o0[u] = a0; o1[u] = a1;
  }

  const int px = tid >> 2, cg = (tid & 3) << 4;
  const int colbase = ccg * 64 + cg;

  // output row 0
#pragma unroll
  for (int u = 0; u < 16; ++u) tile[ch][xp + u] = f2bf(o0[u]);
  __syncthreads();
  {
    us8 v0, v1;
#pragma unroll
    for (int j = 0; j < 8; ++j) v0[j] = tile[cg + j][px];
#pragma unroll
    for (int j = 0; j < 8; ++j) v1[j] = tile[cg + 8 + j][px];
    const long p = ((long)n << 12) + (y0 << 6) + px;
    unsigned short* dst = outT + p * OSTRIDE + colbase;
    *(us8*)dst = v0;
    *(us8*)(dst + 8) = v1;
  }
  __syncthreads();
  // output row 1
#pragma unroll
  for (int u = 0; u < 16; ++u) tile[ch][xp + u] = f2bf(o1[u]);
  __syncthreads();
  {
    us8 v0, v1;
#pragma unroll
    for (int j = 0; j < 8; ++j) v0[j] = tile[cg + j][px];
#pragma unroll
    for (int j = 0; j < 8; ++j) v1[j] = tile[cg + 8 + j][px];
    const long p = ((long)n << 12) + ((y0 + 1) << 6) + px;
    unsigned short* dst = outT + p * OSTRIDE + colbase;
    *(us8*)dst = v0;
    *(us8*)(dst + 8) = v1;
  }
}

// ---------------- 256x256 bf16 MFMA GEMM, safe 2-phase pipeline ----------
// BM=BN=256, BK=32, 8 waves (2M x 4N), per-wave 128x64, acc[8][4].
// LDS: 2 x (A 16KB + B 16KB) = 64KB static.  Per iter {STAGE next tile into
// buf^1; ds_read+MFMA from buf; __syncthreads()}.  Source-side chunk swizzle
// p ^ ((r>>1)&3) (m173), de-swizzled on ds_read -> 2-way = free (m136).
// MODE 0: out = bf16 NCHW (i path), bias from aux.
// MODE 1: fused LSTM epilogue (A = gate-interleaved Wstack; aux = cin;
//   outv = [ch | cc] f32 NCHW).
template<int K, int NT, int MTB, int MODE>
__global__ __launch_bounds__(512, 2) void gemm256_kernel(
    const unsigned short* __restrict__ A,
    const unsigned short* __restrict__ Bt,
    const float* __restrict__ aux,
    void* __restrict__ outv)
{
  __shared__ unsigned short lds[2][16384];
  const int nwg = gridDim.x;
  const int bid = blockIdx.x;
  const int wg  = (bid & 7) * (nwg >> 3) + (bid >> 3); // bijective (nwg%8==0)
  const int m_t = wg & ((1 << MTB) - 1);
  const int n_t = wg >> MTB;
  const int m0 = m_t << 8;
  const long p0 = (long)n_t << 8;

  const int tid = threadIdx.x;
  const int wid = tid >> 6, l = tid & 63;
  const int wr = wid >> 2, wc = wid & 3;
  const int lm = l & 15, lk = l >> 4;

  const int srow = tid >> 2;
  const int cx   = (tid & 3) ^ ((srow >> 1) & 3);
  const unsigned short* gA0 = A + (long)(m0 + srow) * K + cx * 8;
  const unsigned short* gA1 = A + (long)(m0 + 128 + srow) * K + cx * 8;
  const unsigned short* gB0 = Bt + (p0 + srow) * K + cx * 8;
  const unsigned short* gB1 = Bt + (p0 + 128 + srow) * K + cx * 8;
  char* ldsb = (char*)&lds[0][0];

#define STAGE(buf, kt2) { \
    char* nb = ldsb + (buf) * 32768 + wid * 1024; \
    const int ko = (kt2) * 32; \
    gload_lds16(gA0 + ko, nb); \
    gload_lds16(gA1 + ko, nb + 8192); \
    gload_lds16(gB0 + ko, nb + 16384); \
    gload_lds16(gB1 + ko, nb + 24576); }

  int aoff[8], boff[4];
#pragma unroll
  for (int mf = 0; mf < 8; ++mf) {
    const int arow = wr * 128 + mf * 16 + lm;
    aoff[mf] = arow * 64 + ((lk ^ ((lm >> 1) & 3)) * 16);
  }
#pragma unroll
  for (int nf = 0; nf < 4; ++nf) {
    const int brow = wc * 64 + nf * 16 + lm;
    boff[nf] = 16384 + brow * 64 + ((lk ^ ((lm >> 1) & 3)) * 16);
  }

  f32x4 acc[8][4] = {};

  STAGE(0, 0);
  __syncthreads();

#pragma unroll 2
  for (int kt = 0; kt < NT; ++kt) {
    if (kt + 1 < NT) STAGE((kt + 1) & 1, kt + 1);
    const char* cb = ldsb + (kt & 1) * 32768;
    bf16x8_t af[8], bv[4];
#pragma unroll
    for (int mf = 0; mf < 8; ++mf) af[mf] = *(const bf16x8_t*)(cb + aoff[mf]);
#pragma unroll
    for (int nf = 0; nf < 4; ++nf) bv[nf] = *(const bf16x8_t*)(cb + boff[nf]);
#pragma unroll
    for (int mf = 0; mf < 8; ++mf)
#pragma unroll
      for (int nf = 0; nf < 4; ++nf)
        acc[mf][nf] = __builtin_amdgcn_mfma_f32_16x16x32_bf16(
            af[mf], bv[nf], acc[mf][nf], 0, 0, 0);
    __syncthreads();
  }
#undef STAGE

  if (MODE == 0) {
    unsigned short* out = (unsigned short*)outv;
#pragma unroll
    for (int mf = 0; mf < 8; ++mf) {
#pragma unroll
      for (int nf = 0; nf < 4; ++nf) {
#pragma unroll
        for (int j = 0; j < 4; ++j) {
          const int m = m0 + wr * 128 + mf * 16 + lk * 4 + j;
          const long p = p0 + wc * 64 + nf * 16 + lm;
          const float v = acc[mf][nf][j] + aux[m];
          const long oidx = (p >> 12) * (long)(CH * NPIX) + (long)m * NPIX + (p & 4095);
          out[oidx] = f2bf(v);
        }
      }
    }
  } else {
    float* outp = (float*)outv;
    const long CCOFF = (long)NB * CH * NPIX;
#pragma unroll
    for (int sub = 0; sub < 2; ++sub) {
#pragma unroll
      for (int nf = 0; nf < 4; ++nf) {
#pragma unroll
        for (int j = 0; j < 4; ++j) {
          const int chan = (m0 >> 2) + wr * 32 + sub * 16 + lk * 4 + j;
          const long p = p0 + wc * 64 + nf * 16 + lm;
          const long cidx = (p >> 12) * (long)(CH * NPIX) + (long)chan * NPIX + (p & 4095);
          const float zi = acc[0 + sub][nf][j];
          const float zf = acc[2 + sub][nf][j];
          const float zc = acc[4 + sub][nf][j];
          const float zo = acc[6 + sub][nf][j];
          const float ccv = sigmoidf_(zf) * aux[cidx] + sigmoidf_(zi) * relu6f_(zc);
          outp[CCOFF + cidx] = ccv;
          outp[cidx] = sigmoidf_(zo) * relu6f_(ccv);
        }
      }
    }
  }
}

// ---------------- launch ----------------
extern "C" void kernel_launch(void* const* d_in, const int* in_sizes, int n_in,
                              void* d_out, int out_size, void* d_ws, size_t ws_size,
                              hipStream_t stream)
{
  const float* x    = (const float*)d_in[0];
  const float* h    = (const float*)d_in[1];
  const float* c    = (const float*)d_in[2];
  const float* Wdw  = (const float*)d_in[3];
  const float* Wdwb = (const float*)d_in[4];
  const float* Wy   = (const float*)d_in[5];
  const float* Wyb  = (const float*)d_in[6];
  const float* Wi   = (const float*)d_in[7];
  const float* Wbi  = (const float*)d_in[8];
  const float* Wbf  = (const float*)d_in[9];
  const float* Wbc  = (const float*)d_in[10];
  const float* Wbo  = (const float*)d_in[11];
  float* outp = (float*)d_out;

  char* ws = (char*)d_ws;
  // workspace layout (bytes), peak ~91.0 MB:
  //   Y_T  [32768][832] bf16 @ 0            (54,525,952)  dead after gemm1
  //   i_b  [8][512][4096] bf16 @ 54,525,952 (33,554,432)  dead after dwi
  //   b_T  [32768][512] bf16 @ 0            (33,554,432)  overlays dead Y_T
  //   Wy_bf @ 88,080,384 (851,968) ; Wstack @ 88,932,352 (2,097,152)
  unsigned short* Y_T    = (unsigned short*)(ws);
  unsigned short* i_b    = (unsigned short*)(ws + 54525952);
  unsigned short* b_T    = (unsigned short*)(ws);
  unsigned short* Wy_bf  = (unsigned short*)(ws + 88080384);
  unsigned short* Wstack = (unsigned short*)(ws + 88932352);

  wconv_kernel<<<4096, 256, 0, stream>>>(Wy, Wbi, Wbf, Wbc, Wbo, Wy_bf, Wstack);
  dw3x3_kernel<true, true, CIN, KY><<<dim3(32, 5, 8), 256, 0, stream>>>(x, Wdw, Wdwb, Y_T);
  htr_kernel<<<dim3(64, 8, 8), 256, 0, stream>>>(h, Y_T);
  gemm256_kernel<KY, 26, 1, 0><<<256, 512, 0, stream>>>(Wy_bf, Y_T, Wyb, i_b);
  dw3x3_kernel<false, false, CH, CH><<<dim3(32, 8, 8), 256, 0, stream>>>(i_b, Wi, nullptr, b_T);
  gemm256_kernel<CH, 16, 3, 1><<<1024, 512, 0, stream>>>(Wstack, b_T, c, outp);
}